// Round 13
// baseline (217.598 us; speedup 1.0000x reference)
//
#include <hip/hip_runtime.h>

typedef unsigned short u16;
typedef unsigned int   u32;
typedef __bf16 v8bf __attribute__((ext_vector_type(8)));
typedef float  v4f  __attribute__((ext_vector_type(4)));

#define INV_SQRT_W   0.044194173824159216f   // 1/sqrt(512)
#define INV_SQRT_KKC 0.029462782549439483f   // 1/sqrt(3*3*128)
#define LRELU_GAIN   1.4142135623730951f

__device__ __forceinline__ u16 f2bf(float f) {
    u32 u = __float_as_uint(f);
    u = (u + 0x7fffu + ((u >> 16) & 1u)) >> 16;   // RNE
    return (u16)u;
}

__device__ __forceinline__ void glds16(const u16* g, u16* l) {
    __builtin_amdgcn_global_load_lds(
        (const __attribute__((address_space(1))) void*)g,
        (__attribute__((address_space(3))) void*)l, 16, 0, 0);
}

// ---------------- kernel S: s[n,i] = z @ (aw/sqrt(512)) + ab ----------------
__global__ void k_s(const float* __restrict__ dlat,
                    const float* __restrict__ aw,
                    const float* __restrict__ ab,
                    const int*   __restrict__ lidx,
                    float* __restrict__ s_out)
{
    const int n   = blockIdx.x;      // 8
    const int tid = threadIdx.x;     // 256
    const int i   = tid & 127, kh = tid >> 7;
    const int li  = lidx[0];
    const float* z = dlat + (n * 16 + li) * 512 + kh * 256;
    const float* a = aw + kh * 256 * 128 + i;
    float a0 = 0.f, a1 = 0.f, a2 = 0.f, a3 = 0.f;
    for (int k = 0; k < 256; k += 4) {
        a0 += z[k + 0] * a[(k + 0) * 128];
        a1 += z[k + 1] * a[(k + 1) * 128];
        a2 += z[k + 2] * a[(k + 2) * 128];
        a3 += z[k + 3] * a[(k + 3) * 128];
    }
    __shared__ float part[256];
    part[tid] = a0 + a1 + a2 + a3;
    __syncthreads();
    if (tid < 128)
        s_out[n * 128 + i] = (part[i] + part[i + 128]) * INV_SQRT_W + ab[i];
}

// ---------------- kernel W2: W2[i,o] = sum_t (cw[t,i,o]*inv)^2 ----------------
__global__ void k_w2(const float* __restrict__ cw, float* __restrict__ W2)
{
    const int idx = blockIdx.x * 256 + threadIdx.x;   // 16384 = i*128+o
    float acc = 0.f;
    #pragma unroll
    for (int t = 0; t < 9; ++t) {
        float w = cw[t * 16384 + idx];
        acc += w * w;
    }
    W2[idx] = acc * (INV_SQRT_KKC * INV_SQRT_KKC);
}

// ---------------- kernel D: d[n,o] = rsqrt(sum_i W2[i,o]*s2[n,i] + 1e-8) ----------------
__global__ void k_d(const float* __restrict__ W2,
                    const float* __restrict__ s_buf,
                    float* __restrict__ d_out)
{
    const int n = blockIdx.x;   // 8
    const int o = threadIdx.x;  // 128
    __shared__ float s2[128];
    float sv = s_buf[n * 128 + o];
    s2[o] = sv * sv;
    __syncthreads();
    float acc = 1e-8f;
    #pragma unroll 4
    for (int i = 0; i < 128; ++i)
        acc += W2[i * 128 + o] * s2[i];
    d_out[n * 128 + o] = 1.0f / sqrtf(acc);
}

// -------- kernel WMOD: 36 stages of 8KB, layout [g:4][cout:128][8ci] bf16 --------
// stage s = q4*9 + tw*3 + th  (q4: 32-ci block, tap = th*3+tw)  -> th-inner order.
__global__ void k_wmod(const float* __restrict__ cw,
                       const float* __restrict__ s_buf,
                       const float* __restrict__ d_buf,
                       u16* __restrict__ wmod)
{
    const int b   = blockIdx.x;          // 288 = n*36 + s
    const int n   = b / 36;
    const int s   = b - n * 36;
    const int q4  = s / 9;
    const int r   = s - q4 * 9;
    const int tw  = r / 3, th = r - tw * 3;
    const int tap = th * 3 + tw;
    const int cibase = q4 * 32;
    const int tid = threadIdx.x;         // 256
    __shared__ float ssh[32], dsh[128];
    if (tid < 32)  ssh[tid] = s_buf[n * 128 + cibase + tid] * INV_SQRT_KKC;
    if (tid < 128) dsh[tid] = d_buf[n * 128 + tid];
    __syncthreads();
    u16* wt = wmod + ((size_t)b << 12);   // 4096 u16 per stage
    #pragma unroll
    for (int rep = 0; rep < 2; ++rep) {
        int t2   = rep * 256 + tid;       // 512 (g,cout) pairs
        int g    = t2 >> 7;
        int cout = t2 & 127;
        float dv = dsh[cout];
        u32 pk[4];
        #pragma unroll
        for (int jj = 0; jj < 4; ++jj) {
            int cl = g * 8 + jj * 2;
            float v0 = cw[((tap * 128 + cibase + cl) << 7) + cout]     * ssh[cl]     * dv;
            float v1 = cw[((tap * 128 + cibase + cl + 1) << 7) + cout] * ssh[cl + 1] * dv;
            pk[jj] = (u32)f2bf(v0) | ((u32)f2bf(v1) << 16);
        }
        *(uint4*)&wt[(g << 10) + (cout << 3)] = *(uint4*)pk;
    }
}

// ---------------- kernel CONV: R12 + 3-slot B ring + counted vmcnt (T4) ----------------
// 256 threads = 4 waves (2M x 2N); block tile 128 px (8h x 16w) x 128 cout; grid 4096.
// Wave: 64 px x 64 cout (acc[4][4], 64 AGPR). 36 stages (K=32), th-inner af[6] reuse.
// xs: ci-half halo, 8 slabs x 1448 u16 (conflict-free staging), restaged once.
// B: bsh 3-slot ring (3x8KB), glds depth-2 prefetch; per step: s_waitcnt vmcnt(2)
// (stage resident, next stays IN FLIGHT across the barrier - never drain to 0),
// raw s_barrier, reads, issue glds(T+2) into slot (T+2)%3, MFMA.
// LDS 47.7KB -> 3 blocks/CU = 12 waves/CU.
template<int T>
__device__ __forceinline__ void conv_step(const u16* __restrict__ wn,
                                          u16* __restrict__ bsh,
                                          const u16* a_base,
                                          const u16* b_lane,
                                          v8bf af[6], v4f acc[4][4],
                                          int wid, int lane)
{
    constexpr int q4 = T / 9, r = T % 9, tw = r / 3, th = r % 3;
    constexpr int slot = T % 3;
    constexpr int hq = q4 & 1;
    // counted wait: stage T resident (in-order vmcnt retire); stage T+1's 2 glds
    // remain in flight across the barrier. lgkmcnt(0) at 0/18 publishes A ds_writes.
    if constexpr (T == 0 || T == 18)
        asm volatile("s_waitcnt vmcnt(2) lgkmcnt(0)" ::: "memory");
    else if constexpr (T == 35)
        asm volatile("s_waitcnt vmcnt(0)" ::: "memory");
    else
        asm volatile("s_waitcnt vmcnt(2)" ::: "memory");
    __builtin_amdgcn_s_barrier();
    asm volatile("" ::: "memory");

    v8bf bf[4];
    #pragma unroll
    for (int ni = 0; ni < 4; ++ni)
        bf[ni] = *(const v8bf*)(b_lane + slot * 4096 + (ni << 7));
    if constexpr (th == 0) {
        #pragma unroll
        for (int j = 0; j < 6; ++j)
            af[j] = *(const v8bf*)(a_base + hq * 5792 + (j * 18 + tw) * 8);
    }
    if constexpr (T + 2 < 36) {          // prefetch stage T+2 into slot (T+2)%3
        constexpr int ns = (T + 2) % 3;  // (all waves finished reading it pre-barrier)
        #pragma unroll
        for (int t = 0; t < 2; ++t) {
            int chunk = wid + (t << 2);
            glds16(wn + (T + 2) * 4096 + (chunk << 9) + (lane << 3),
                   &bsh[ns * 4096 + (chunk << 9) + (lane << 3)]);
        }
    }
    #pragma unroll
    for (int mi = 0; mi < 4; ++mi)
        #pragma unroll
        for (int ni = 0; ni < 4; ++ni)
            acc[mi][ni] = __builtin_amdgcn_mfma_f32_16x16x32_bf16(
                af[mi + th], bf[ni], acc[mi][ni], 0, 0, 0);
}

__global__ __launch_bounds__(256, 3) void k_conv(
    const float* __restrict__ x,
    const float* __restrict__ noise,
    const float* __restrict__ conv_b,
    const float* __restrict__ nstr,
    const u16*   __restrict__ wmod,
    float* __restrict__ out)
{
    __shared__ __align__(16) u16 xs[11584];       // 8 slabs x 1448 u16 (ci-half halo)
    __shared__ __align__(16) u16 bsh[12288];      // 3-slot B ring, 8KB each

    const int bid0 = blockIdx.x;
    const int bid  = ((bid0 & 7) << 9) + (bid0 >> 3);   // XCD swizzle (4096%8==0, bijective)
    const int n   = bid >> 9;
    const int hb  = (bid >> 4) & 31;
    const int wb  = bid & 15;
    const int h0  = hb << 3, w0 = wb << 4;

    const int tid  = threadIdx.x;
    const int lane = tid & 63;
    const int wid  = tid >> 6;
    const int wm   = wid >> 1;         // M half (rows wm*4..wm*4+3)
    const int wq   = wid & 1;          // N half (couts wq*64..)
    const int lr   = lane & 15;
    const int kg   = lane >> 4;

    const float* xbase = x + ((size_t)n << 16) * 128;

    // ---- stage X halo half (10 x 18 x 64ci) fp32 -> bf16, conflict-free stride ----
    #define STAGE_X(ph)                                                              \
    for (int t = tid; t < 1440; t += 256) {                                          \
        int q = t >> 3, g = t & 7;                                                   \
        int rr_ = q / 18, cc = q - rr_ * 18;                                         \
        int gh = h0 + rr_ - 1, gw = w0 + cc - 1;                                     \
        float v0=0.f,v1=0.f,v2=0.f,v3=0.f,v4=0.f,v5=0.f,v6=0.f,v7=0.f;               \
        if ((unsigned)gh < 256u && (unsigned)gw < 256u) {                            \
            const float* src = xbase + (size_t)((gh << 8) + gw) * 128                \
                               + (ph) * 64 + (g << 3);                               \
            float4 fa = *(const float4*)(src);                                       \
            float4 fb = *(const float4*)(src + 4);                                   \
            v0=fa.x; v1=fa.y; v2=fa.z; v3=fa.w; v4=fb.x; v5=fb.y; v6=fb.z; v7=fb.w;  \
        }                                                                            \
        v8bf pk;                                                                     \
        pk[0]=(__bf16)v0; pk[1]=(__bf16)v1; pk[2]=(__bf16)v2; pk[3]=(__bf16)v3;      \
        pk[4]=(__bf16)v4; pk[5]=(__bf16)v5; pk[6]=(__bf16)v6; pk[7]=(__bf16)v7;      \
        *(v8bf*)&xs[g * 1448 + q * 8] = pk;                                          \
    }

    STAGE_X(0)

    // ---- prologue: issue glds for B stages 0,1 into ring slots 0,1 ----
    const u16* wn = wmod + ((size_t)n * 36) * 4096;
    #pragma unroll
    for (int s0 = 0; s0 < 2; ++s0)
        #pragma unroll
        for (int t = 0; t < 2; ++t) {
            int chunk = wid + (t << 2);
            glds16(wn + s0 * 4096 + (chunk << 9) + (lane << 3),
                   &bsh[s0 * 4096 + (chunk << 9) + (lane << 3)]);
        }

    v4f acc[4][4];
    #pragma unroll
    for (int a = 0; a < 4; ++a)
        #pragma unroll
        for (int b2 = 0; b2 < 4; ++b2) {
            v4f zz = {0.f, 0.f, 0.f, 0.f};
            acc[a][b2] = zz;
        }

    const u16* const a_base = &xs[kg * 1448 + (wm * 72 + lr) * 8];
    const u16* const b_lane = &bsh[kg * 1024 + (wq * 64 + lr) * 8];

    v8bf af[6];
    // step 0's wait (vmcnt(2)+lgkmcnt(0)) + barrier publishes xs half-0 and B stage 0
    conv_step< 0>(wn, bsh, a_base, b_lane, af, acc, wid, lane);
    conv_step< 1>(wn, bsh, a_base, b_lane, af, acc, wid, lane);
    conv_step< 2>(wn, bsh, a_base, b_lane, af, acc, wid, lane);
    conv_step< 3>(wn, bsh, a_base, b_lane, af, acc, wid, lane);
    conv_step< 4>(wn, bsh, a_base, b_lane, af, acc, wid, lane);
    conv_step< 5>(wn, bsh, a_base, b_lane, af, acc, wid, lane);
    conv_step< 6>(wn, bsh, a_base, b_lane, af, acc, wid, lane);
    conv_step< 7>(wn, bsh, a_base, b_lane, af, acc, wid, lane);
    conv_step< 8>(wn, bsh, a_base, b_lane, af, acc, wid, lane);
    conv_step< 9>(wn, bsh, a_base, b_lane, af, acc, wid, lane);
    conv_step<10>(wn, bsh, a_base, b_lane, af, acc, wid, lane);
    conv_step<11>(wn, bsh, a_base, b_lane, af, acc, wid, lane);
    conv_step<12>(wn, bsh, a_base, b_lane, af, acc, wid, lane);
    conv_step<13>(wn, bsh, a_base, b_lane, af, acc, wid, lane);
    conv_step<14>(wn, bsh, a_base, b_lane, af, acc, wid, lane);
    conv_step<15>(wn, bsh, a_base, b_lane, af, acc, wid, lane);
    conv_step<16>(wn, bsh, a_base, b_lane, af, acc, wid, lane);
    conv_step<17>(wn, bsh, a_base, b_lane, af, acc, wid, lane);

    // restage xs to ci 64..127 (no wave reads xs after its step-15 af load; all
    // waves passed barrier(17-top)). Published by step 18's lgkmcnt(0)+barrier.
    STAGE_X(1)

    conv_step<18>(wn, bsh, a_base, b_lane, af, acc, wid, lane);
    conv_step<19>(wn, bsh, a_base, b_lane, af, acc, wid, lane);
    conv_step<20>(wn, bsh, a_base, b_lane, af, acc, wid, lane);
    conv_step<21>(wn, bsh, a_base, b_lane, af, acc, wid, lane);
    conv_step<22>(wn, bsh, a_base, b_lane, af, acc, wid, lane);
    conv_step<23>(wn, bsh, a_base, b_lane, af, acc, wid, lane);
    conv_step<24>(wn, bsh, a_base, b_lane, af, acc, wid, lane);
    conv_step<25>(wn, bsh, a_base, b_lane, af, acc, wid, lane);
    conv_step<26>(wn, bsh, a_base, b_lane, af, acc, wid, lane);
    conv_step<27>(wn, bsh, a_base, b_lane, af, acc, wid, lane);
    conv_step<28>(wn, bsh, a_base, b_lane, af, acc, wid, lane);
    conv_step<29>(wn, bsh, a_base, b_lane, af, acc, wid, lane);
    conv_step<30>(wn, bsh, a_base, b_lane, af, acc, wid, lane);
    conv_step<31>(wn, bsh, a_base, b_lane, af, acc, wid, lane);
    conv_step<32>(wn, bsh, a_base, b_lane, af, acc, wid, lane);
    conv_step<33>(wn, bsh, a_base, b_lane, af, acc, wid, lane);
    conv_step<34>(wn, bsh, a_base, b_lane, af, acc, wid, lane);
    conv_step<35>(wn, bsh, a_base, b_lane, af, acc, wid, lane);

    // ---- epilogue: + noise*strength + bias, lrelu * sqrt(2) ----
    const float ns = nstr[0];
    float cb4[4];
    #pragma unroll
    for (int ni = 0; ni < 4; ++ni)
        cb4[ni] = conv_b[wq * 64 + ni * 16 + lr];
    #pragma unroll
    for (int mi = 0; mi < 4; ++mi) {
        const int h = h0 + wm * 4 + mi;
        #pragma unroll
        for (int j = 0; j < 4; ++j) {
            const int w  = w0 + kg * 4 + j;
            const float nz = noise[((n << 8) + h) * 256 + w] * ns;
            float* orow = out + (size_t)((((n << 8) + h) << 8) + w) * 128;
            #pragma unroll
            for (int ni = 0; ni < 4; ++ni) {
                const int cout = wq * 64 + ni * 16 + lr;
                float v = acc[mi][ni][j] + nz + cb4[ni];
                v = (v < 0.f ? 0.2f * v : v) * LRELU_GAIN;
                orow[cout] = v;
            }
        }
    }
}

extern "C" void kernel_launch(void* const* d_in, const int* in_sizes, int n_in,
                              void* d_out, int out_size, void* d_ws, size_t ws_size,
                              hipStream_t stream) {
    const float* x     = (const float*)d_in[0];
    const float* dlat  = (const float*)d_in[1];
    const float* noise = (const float*)d_in[2];
    const float* aw    = (const float*)d_in[3];
    const float* ab    = (const float*)d_in[4];
    const float* cw    = (const float*)d_in[5];
    const float* cb    = (const float*)d_in[6];
    const float* nstr  = (const float*)d_in[7];
    const int*   lidx  = (const int*)d_in[8];
    float* out = (float*)d_out;

    float* s_buf = (float*)d_ws;                               // 4KB
    float* d_buf = (float*)((char*)d_ws + 4096);               // 4KB
    float* W2    = (float*)((char*)d_ws + 8192);
    u16*   wmod  = (u16*)((char*)d_ws + 8192);                 // 2.25MB (aliases W2, ordered)

    k_w2  <<<64,  256, 0, stream>>>(cw, W2);
    k_s   <<<8,   256, 0, stream>>>(dlat, aw, ab, lidx, s_buf);
    k_d   <<<8,   128, 0, stream>>>(W2, s_buf, d_buf);
    k_wmod<<<288, 256, 0, stream>>>(cw, s_buf, d_buf, wmod);
    k_conv<<<4096,256, 0, stream>>>(x, noise, cb, nstr, wmod, out);
}

// Round 14
// 194.770 us; speedup vs baseline: 1.1172x; 1.1172x over previous
//
#include <hip/hip_runtime.h>

typedef unsigned short u16;
typedef unsigned int   u32;
typedef __bf16 v8bf __attribute__((ext_vector_type(8)));
typedef float  v4f  __attribute__((ext_vector_type(4)));

#define INV_SQRT_W   0.044194173824159216f   // 1/sqrt(512)
#define INV_SQRT_KKC 0.029462782549439483f   // 1/sqrt(3*3*128)
#define LRELU_GAIN   1.4142135623730951f

__device__ __forceinline__ u16 f2bf(float f) {
    u32 u = __float_as_uint(f);
    u = (u + 0x7fffu + ((u >> 16) & 1u)) >> 16;   // RNE
    return (u16)u;
}

__device__ __forceinline__ void glds16(const u16* g, u16* l) {
    __builtin_amdgcn_global_load_lds(
        (const __attribute__((address_space(1))) void*)g,
        (__attribute__((address_space(3))) void*)l, 16, 0, 0);
}

// ---------------- kernel S1: partial dot, 32 blocks (n x 4 k-chunks) ----------------
__global__ void k_s1(const float* __restrict__ dlat,
                     const float* __restrict__ aw,
                     const int*   __restrict__ lidx,
                     float* __restrict__ part)
{
    const int b   = blockIdx.x;        // 32 = n*4 + kh
    const int n   = b >> 2, kh = b & 3;
    const int tid = threadIdx.x;       // 256
    const int i   = tid & 127, half = tid >> 7;
    const int li  = lidx[0];
    const float* z = dlat + (n * 16 + li) * 512 + kh * 128 + half * 64;
    const float* a = aw + (kh * 128 + half * 64) * 128 + i;
    float a0 = 0.f, a1 = 0.f;
    #pragma unroll 8
    for (int k = 0; k < 64; k += 2) {
        a0 += z[k]     * a[k * 128];
        a1 += z[k + 1] * a[(k + 1) * 128];
    }
    __shared__ float red[256];
    red[tid] = a0 + a1;
    __syncthreads();
    if (tid < 128)
        part[b * 128 + i] = red[i] + red[i + 128];
}

// ---------------- kernel S2: s[n,i] = sum(part)*inv + ab ----------------
__global__ void k_s2(const float* __restrict__ part,
                     const float* __restrict__ ab,
                     float* __restrict__ s_out)
{
    const int n = blockIdx.x, i = threadIdx.x;   // 8 x 128
    float s = part[(n * 4 + 0) * 128 + i] + part[(n * 4 + 1) * 128 + i]
            + part[(n * 4 + 2) * 128 + i] + part[(n * 4 + 3) * 128 + i];
    s_out[n * 128 + i] = s * INV_SQRT_W + ab[i];
}

// ---------------- kernel W2: W2[i,o] = sum_t (cw[t,i,o]*inv)^2 ----------------
__global__ void k_w2(const float* __restrict__ cw, float* __restrict__ W2)
{
    const int idx = blockIdx.x * 256 + threadIdx.x;   // 16384 = i*128+o
    float acc = 0.f;
    #pragma unroll
    for (int t = 0; t < 9; ++t) {
        float w = cw[t * 16384 + idx];
        acc += w * w;
    }
    W2[idx] = acc * (INV_SQRT_KKC * INV_SQRT_KKC);
}

// ---------------- kernel D: d[n,o] = rsqrt(sum_i W2[i,o]*s2[n,i] + 1e-8) ----------------
__global__ void k_d(const float* __restrict__ W2,
                    const float* __restrict__ s_buf,
                    float* __restrict__ d_out)
{
    const int n = blockIdx.x;   // 8
    const int o = threadIdx.x;  // 128
    __shared__ float s2[128];
    float sv = s_buf[n * 128 + o];
    s2[o] = sv * sv;
    __syncthreads();
    float acc = 1e-8f;
    #pragma unroll 4
    for (int i = 0; i < 128; ++i)
        acc += W2[i * 128 + o] * s2[i];
    d_out[n * 128 + o] = 1.0f / sqrtf(acc);
}

// -------- kernel WMOD: 36 stages of 8KB, layout [g:4][cout:128][8ci] bf16 --------
// stage s = q4*9 + tw*3 + th  (q4: 32-ci block, tap = th*3+tw)  -> th-inner order.
__global__ void k_wmod(const float* __restrict__ cw,
                       const float* __restrict__ s_buf,
                       const float* __restrict__ d_buf,
                       u16* __restrict__ wmod)
{
    const int b   = blockIdx.x;          // 288 = n*36 + s
    const int n   = b / 36;
    const int s   = b - n * 36;
    const int q4  = s / 9;
    const int r   = s - q4 * 9;
    const int tw  = r / 3, th = r - tw * 3;
    const int tap = th * 3 + tw;
    const int cibase = q4 * 32;
    const int tid = threadIdx.x;         // 256
    __shared__ float ssh[32], dsh[128];
    if (tid < 32)  ssh[tid] = s_buf[n * 128 + cibase + tid] * INV_SQRT_KKC;
    if (tid < 128) dsh[tid] = d_buf[n * 128 + tid];
    __syncthreads();
    u16* wt = wmod + ((size_t)b << 12);   // 4096 u16 per stage
    #pragma unroll
    for (int rep = 0; rep < 2; ++rep) {
        int t2   = rep * 256 + tid;       // 512 (g,cout) pairs
        int g    = t2 >> 7;
        int cout = t2 & 127;
        float dv = dsh[cout];
        u32 pk[4];
        #pragma unroll
        for (int jj = 0; jj < 4; ++jj) {
            int cl = g * 8 + jj * 2;
            float v0 = cw[((tap * 128 + cibase + cl) << 7) + cout]     * ssh[cl]     * dv;
            float v1 = cw[((tap * 128 + cibase + cl + 1) << 7) + cout] * ssh[cl + 1] * dv;
            pk[jj] = (u32)f2bf(v0) | ((u32)f2bf(v1) << 16);
        }
        *(uint4*)&wt[(g << 10) + (cout << 3)] = *(uint4*)pk;
    }
}

// ---------------- kernel CONV: 256px x 128cout, 8 waves, B ring + counted vmcnt ----------------
// 512 thr = 8 waves (4M x 2N); block tile 256 px (16h x 16w) x 128 cout; grid 2048.
// Wave: 64 px (4h x 16w) x 64 cout, acc[4][4] (64 AGPR), th-inner af[6] reuse.
// A: xs halo 18x18 x 64ci = 8 slabs x 2600 u16 (41.6KB, conflict-free writes), restaged once.
// B: bsh 3-slot ring (3x8KB), 1 glds/thread/stage, s_waitcnt vmcnt(1) per step
// (next stage stays in flight across barrier - T4). LDS 66.2KB -> 2 blocks/CU.
template<int T>
__device__ __forceinline__ void conv_step(const u16* __restrict__ wn,
                                          u16* __restrict__ bsh,
                                          const u16* a_base,
                                          const u16* b_lane,
                                          v8bf af[6], v4f acc[4][4],
                                          int wid, int lane)
{
    constexpr int q4 = T / 9, r = T % 9, tw = r / 3, th = r % 3;
    constexpr int slot = T % 3;
    constexpr int hq = q4 & 1;
    // counted wait: stage T's 1 glds retired (in-order); stage T+1's stays in flight.
    if constexpr (T == 0 || T == 18)
        asm volatile("s_waitcnt vmcnt(1) lgkmcnt(0)" ::: "memory");
    else if constexpr (T == 35)
        asm volatile("s_waitcnt vmcnt(0)" ::: "memory");
    else
        asm volatile("s_waitcnt vmcnt(1)" ::: "memory");
    __builtin_amdgcn_s_barrier();
    asm volatile("" ::: "memory");

    v8bf bf[4];
    #pragma unroll
    for (int ni = 0; ni < 4; ++ni)
        bf[ni] = *(const v8bf*)(b_lane + slot * 4096 + (ni << 7));
    if constexpr (th == 0) {
        #pragma unroll
        for (int j = 0; j < 6; ++j)
            af[j] = *(const v8bf*)(a_base + hq * 10400 + (j * 18 + tw) * 8);
    }
    if constexpr (T + 2 < 36) {          // prefetch stage T+2 into slot (T+2)%3
        constexpr int ns = (T + 2) % 3;
        glds16(wn + (T + 2) * 4096 + (wid << 9) + (lane << 3),
               &bsh[ns * 4096 + (wid << 9) + (lane << 3)]);
    }
    #pragma unroll
    for (int mi = 0; mi < 4; ++mi)
        #pragma unroll
        for (int ni = 0; ni < 4; ++ni)
            acc[mi][ni] = __builtin_amdgcn_mfma_f32_16x16x32_bf16(
                af[mi + th], bf[ni], acc[mi][ni], 0, 0, 0);
}

__global__ __launch_bounds__(512, 4) void k_conv(
    const float* __restrict__ x,
    const float* __restrict__ noise,
    const float* __restrict__ conv_b,
    const float* __restrict__ nstr,
    const u16*   __restrict__ wmod,
    float* __restrict__ out)
{
    __shared__ __align__(16) u16 xs[20800];       // 8 slabs x 2600 u16 (18x18 halo, 64ci)
    __shared__ __align__(16) u16 bsh[12288];      // 3-slot B ring, 8KB each

    const int bid0 = blockIdx.x;
    const int bid  = ((bid0 & 7) << 8) + (bid0 >> 3);   // XCD swizzle (2048%8==0, bijective)
    const int n   = bid >> 8;
    const int hb  = (bid >> 4) & 15;
    const int wb  = bid & 15;
    const int h0  = hb << 4, w0 = wb << 4;

    const int tid  = threadIdx.x;      // 0..511
    const int lane = tid & 63;
    const int wid  = tid >> 6;         // 0..7
    const int wm   = wid >> 1;         // M quarter (rows wm*4..wm*4+3)
    const int wn_  = wid & 1;          // N half (couts wn_*64..)
    const int lr   = lane & 15;
    const int kg   = lane >> 4;

    const float* xbase = x + ((size_t)n << 16) * 128;

    // ---- stage X halo half (18 x 18 x 64ci) fp32 -> bf16, conflict-free slabs ----
    // item t: q = t>>3 (pixel 0..323), g = t&7 (8ci granule). 8 consecutive threads
    // share q (256B contiguous global read); slab stride 2600 u16 (g*1300 mod 32
    // = {0,20,8,28,16,4,24,12} distinct -> ds_write conflict-free).
    #define STAGE_X(ph)                                                              \
    for (int t = tid; t < 2592; t += 512) {                                          \
        int q = t >> 3, g = t & 7;                                                   \
        int rr_ = q / 18, cc = q - rr_ * 18;                                         \
        int gh = h0 + rr_ - 1, gw = w0 + cc - 1;                                     \
        float v0=0.f,v1=0.f,v2=0.f,v3=0.f,v4=0.f,v5=0.f,v6=0.f,v7=0.f;               \
        if ((unsigned)gh < 256u && (unsigned)gw < 256u) {                            \
            const float* src = xbase + (size_t)((gh << 8) + gw) * 128                \
                               + (ph) * 64 + (g << 3);                               \
            float4 fa = *(const float4*)(src);                                       \
            float4 fb = *(const float4*)(src + 4);                                   \
            v0=fa.x; v1=fa.y; v2=fa.z; v3=fa.w; v4=fb.x; v5=fb.y; v6=fb.z; v7=fb.w;  \
        }                                                                            \
        v8bf pk;                                                                     \
        pk[0]=(__bf16)v0; pk[1]=(__bf16)v1; pk[2]=(__bf16)v2; pk[3]=(__bf16)v3;      \
        pk[4]=(__bf16)v4; pk[5]=(__bf16)v5; pk[6]=(__bf16)v6; pk[7]=(__bf16)v7;      \
        *(v8bf*)&xs[g * 2600 + q * 8] = pk;                                          \
    }

    STAGE_X(0)

    // ---- prologue: issue glds for B stages 0,1 into ring slots 0,1 (1 op each) ----
    const u16* wn = wmod + ((size_t)n * 36) * 4096;
    #pragma unroll
    for (int s0 = 0; s0 < 2; ++s0)
        glds16(wn + s0 * 4096 + (wid << 9) + (lane << 3),
               &bsh[s0 * 4096 + (wid << 9) + (lane << 3)]);

    v4f acc[4][4];
    #pragma unroll
    for (int a = 0; a < 4; ++a)
        #pragma unroll
        for (int b2 = 0; b2 < 4; ++b2) {
            v4f zz = {0.f, 0.f, 0.f, 0.f};
            acc[a][b2] = zz;
        }

    // per-lane bases: A slab = kg, rows wm*4.., col lr; B = [g:kg][cout][8ci]
    const u16* const a_base = &xs[kg * 2600 + (wm * 72 + lr) * 8];
    const u16* const b_lane = &bsh[kg * 1024 + (wn_ * 64 + lr) * 8];

    v8bf af[6];
    // step 0's wait (vmcnt(1)+lgkmcnt(0)) + barrier publishes xs half-0 and B stage 0
    conv_step< 0>(wn, bsh, a_base, b_lane, af, acc, wid, lane);
    conv_step< 1>(wn, bsh, a_base, b_lane, af, acc, wid, lane);
    conv_step< 2>(wn, bsh, a_base, b_lane, af, acc, wid, lane);
    conv_step< 3>(wn, bsh, a_base, b_lane, af, acc, wid, lane);
    conv_step< 4>(wn, bsh, a_base, b_lane, af, acc, wid, lane);
    conv_step< 5>(wn, bsh, a_base, b_lane, af, acc, wid, lane);
    conv_step< 6>(wn, bsh, a_base, b_lane, af, acc, wid, lane);
    conv_step< 7>(wn, bsh, a_base, b_lane, af, acc, wid, lane);
    conv_step< 8>(wn, bsh, a_base, b_lane, af, acc, wid, lane);
    conv_step< 9>(wn, bsh, a_base, b_lane, af, acc, wid, lane);
    conv_step<10>(wn, bsh, a_base, b_lane, af, acc, wid, lane);
    conv_step<11>(wn, bsh, a_base, b_lane, af, acc, wid, lane);
    conv_step<12>(wn, bsh, a_base, b_lane, af, acc, wid, lane);
    conv_step<13>(wn, bsh, a_base, b_lane, af, acc, wid, lane);
    conv_step<14>(wn, bsh, a_base, b_lane, af, acc, wid, lane);
    conv_step<15>(wn, bsh, a_base, b_lane, af, acc, wid, lane);
    conv_step<16>(wn, bsh, a_base, b_lane, af, acc, wid, lane);
    conv_step<17>(wn, bsh, a_base, b_lane, af, acc, wid, lane);

    // restage xs to ci 64..127 (last xs reads were step-15 af loads, all waves past
    // barrier(17)); published by step 18's lgkmcnt(0)+barrier.
    STAGE_X(1)

    conv_step<18>(wn, bsh, a_base, b_lane, af, acc, wid, lane);
    conv_step<19>(wn, bsh, a_base, b_lane, af, acc, wid, lane);
    conv_step<20>(wn, bsh, a_base, b_lane, af, acc, wid, lane);
    conv_step<21>(wn, bsh, a_base, b_lane, af, acc, wid, lane);
    conv_step<22>(wn, bsh, a_base, b_lane, af, acc, wid, lane);
    conv_step<23>(wn, bsh, a_base, b_lane, af, acc, wid, lane);
    conv_step<24>(wn, bsh, a_base, b_lane, af, acc, wid, lane);
    conv_step<25>(wn, bsh, a_base, b_lane, af, acc, wid, lane);
    conv_step<26>(wn, bsh, a_base, b_lane, af, acc, wid, lane);
    conv_step<27>(wn, bsh, a_base, b_lane, af, acc, wid, lane);
    conv_step<28>(wn, bsh, a_base, b_lane, af, acc, wid, lane);
    conv_step<29>(wn, bsh, a_base, b_lane, af, acc, wid, lane);
    conv_step<30>(wn, bsh, a_base, b_lane, af, acc, wid, lane);
    conv_step<31>(wn, bsh, a_base, b_lane, af, acc, wid, lane);
    conv_step<32>(wn, bsh, a_base, b_lane, af, acc, wid, lane);
    conv_step<33>(wn, bsh, a_base, b_lane, af, acc, wid, lane);
    conv_step<34>(wn, bsh, a_base, b_lane, af, acc, wid, lane);
    conv_step<35>(wn, bsh, a_base, b_lane, af, acc, wid, lane);

    // ---- epilogue: + noise*strength + bias, lrelu * sqrt(2) ----
    const float ns = nstr[0];
    float cb4[4];
    #pragma unroll
    for (int ni = 0; ni < 4; ++ni)
        cb4[ni] = conv_b[wn_ * 64 + ni * 16 + lr];
    #pragma unroll
    for (int mi = 0; mi < 4; ++mi) {
        const int h = h0 + wm * 4 + mi;
        #pragma unroll
        for (int j = 0; j < 4; ++j) {
            const int w  = w0 + kg * 4 + j;
            const float nz = noise[((n << 8) + h) * 256 + w] * ns;
            float* orow = out + (size_t)((((n << 8) + h) << 8) + w) * 128;
            #pragma unroll
            for (int ni = 0; ni < 4; ++ni) {
                const int cout = wn_ * 64 + ni * 16 + lr;
                float v = acc[mi][ni][j] + nz + cb4[ni];
                v = (v < 0.f ? 0.2f * v : v) * LRELU_GAIN;
                orow[cout] = v;
            }
        }
    }
}

extern "C" void kernel_launch(void* const* d_in, const int* in_sizes, int n_in,
                              void* d_out, int out_size, void* d_ws, size_t ws_size,
                              hipStream_t stream) {
    const float* x     = (const float*)d_in[0];
    const float* dlat  = (const float*)d_in[1];
    const float* noise = (const float*)d_in[2];
    const float* aw    = (const float*)d_in[3];
    const float* ab    = (const float*)d_in[4];
    const float* cw    = (const float*)d_in[5];
    const float* cb    = (const float*)d_in[6];
    const float* nstr  = (const float*)d_in[7];
    const int*   lidx  = (const int*)d_in[8];
    float* out = (float*)d_out;

    float* s_buf = (float*)d_ws;                               // 4KB
    float* d_buf = (float*)((char*)d_ws + 4096);               // 4KB
    float* W2    = (float*)((char*)d_ws + 8192);
    u16*   wmod  = (u16*)((char*)d_ws + 8192);                 // 2.25MB (aliases W2, ordered)
    float* part  = (float*)((char*)d_ws + 8192 + 2359296);     // 16KB partials for k_s

    k_w2  <<<64,  256, 0, stream>>>(cw, W2);
    k_s1  <<<32,  256, 0, stream>>>(dlat, aw, lidx, part);
    k_s2  <<<8,   128, 0, stream>>>(part, ab, s_buf);
    k_d   <<<8,   128, 0, stream>>>(W2, s_buf, d_buf);
    k_wmod<<<288, 256, 0, stream>>>(cw, s_buf, d_buf, wmod);
    k_conv<<<2048,512, 0, stream>>>(x, noise, cb, nstr, wmod, out);
}